// Round 5
// baseline (931.490 us; speedup 1.0000x reference)
//
#include <hip/hip_runtime.h>

#define B_ 8
#define S_ 1024
#define D_ 768
#define H_ 12
#define DH_ 64

typedef __attribute__((ext_vector_type(8))) short short8;
typedef __attribute__((ext_vector_type(4))) short short4v;
typedef __attribute__((ext_vector_type(4))) float float4v;
typedef __attribute__((ext_vector_type(8))) __bf16 bf16x8;

static __device__ __forceinline__ short f2bf(float f) {
  union { float f; unsigned u; } v; v.f = f;
  unsigned r = v.u + 0x7fffu + ((v.u >> 16) & 1u);
  return (short)(r >> 16);
}
static __device__ __forceinline__ float bf2f(short s) {
  union { unsigned u; float f; } v; v.u = ((unsigned)(unsigned short)s) << 16;
  return v.f;
}

static __device__ __forceinline__ float4v mfma16(const short* ap, const short* bp, float4v c) {
  bf16x8 a = *(const bf16x8*)ap;
  bf16x8 b = *(const bf16x8*)bp;
  return __builtin_amdgcn_mfma_f32_16x16x32_bf16(a, b, c, 0, 0, 0);
}

typedef const __attribute__((address_space(1))) unsigned gu32;
typedef __attribute__((address_space(3))) unsigned lu32;
static __device__ __forceinline__ void gload16(const void* g, void* l) {
  __builtin_amdgcn_global_load_lds((gu32*)g, (lu32*)l, 16, 0, 0);
}

// ---------------- fp32 -> bf16 conversion (hidden states) ----------------
__global__ __launch_bounds__(256) void cvt_bf16(const float* __restrict__ src,
                                                short* __restrict__ dst, int n4) {
  int i = blockIdx.x * 256 + threadIdx.x;
  if (i < n4) {
    float4v v = ((const float4v*)src)[i];
    short4v o;
    o.x = f2bf(v.x); o.y = f2bf(v.y); o.z = f2bf(v.z); o.w = f2bf(v.w);
    ((short4v*)dst)[i] = o;
  }
}

// ---------------- all 4 weight matrices in one launch ----------------
// 576 blocks per weight (589824 elems / 4 / 256)
__global__ __launch_bounds__(256) void cvt_w4(const float* __restrict__ w0,
                                              const float* __restrict__ w1,
                                              const float* __restrict__ w2,
                                              const float* __restrict__ w3,
                                              short* __restrict__ wqkv,
                                              short* __restrict__ wob) {
  int seg = blockIdx.x / 576, loc = blockIdx.x % 576;
  const float* src = (seg == 0) ? w0 : (seg == 1) ? w1 : (seg == 2) ? w2 : w3;
  short* dst = (seg < 3) ? (wqkv + (size_t)seg * 589824) : wob;
  int i = loc * 256 + threadIdx.x;
  float4v v = ((const float4v*)src)[i];
  short4v o;
  o.x = f2bf(v.x); o.y = f2bf(v.y); o.z = f2bf(v.z); o.w = f2bf(v.w);
  ((short4v*)dst)[i] = o;
}

// ---------------- QKV projection GEMM (NT): C[8192][2304] = hs_bf16 @ Wqkv^T ----------------
__global__ __launch_bounds__(256) void gemm_qkv(const short* __restrict__ A,
                                                const short* __restrict__ Bw,
                                                const float* __restrict__ bq,
                                                const float* __restrict__ bk,
                                                const float* __restrict__ bv,
                                                short* __restrict__ Qb,
                                                short* __restrict__ Kb,
                                                short* __restrict__ Vtb) {
  __shared__ char smem[34816];                       // Cs[128][136] overlay; As+Bs = 16KB
  short (*As)[32] = (short(*)[32])smem;
  short (*Bs)[32] = (short(*)[32])(smem + 8192);
  short (*Cs)[136] = (short(*)[136])smem;

  int m0 = blockIdx.x * 128, n0 = blockIdx.y * 128;
  int t = threadIdx.x, w = t >> 6, lane = t & 63;
  int wm = (w >> 1) * 64, wn = (w & 1) * 64;
  int lr = lane & 15, lk = (lane >> 4) * 8;

  const short* gA = A + (size_t)(m0 + w * 32 + (lane >> 2)) * 768 + (lane & 3) * 8;
  const short* gB = Bw + (size_t)(n0 + w * 32 + (lane >> 2)) * 768 + (lane & 3) * 8;

  float4v acc[4][4] = {};

  for (int k0 = 0; k0 < 768; k0 += 32) {
    gload16(gA, &As[w * 32][0]);
    gload16(gA + 16 * 768, &As[w * 32 + 16][0]);
    gload16(gB, &Bs[w * 32][0]);
    gload16(gB + 16 * 768, &Bs[w * 32 + 16][0]);
    gA += 32; gB += 32;
    __syncthreads();
    short8 a[4], b[4];
#pragma unroll
    for (int i = 0; i < 4; i++) a[i] = *(const short8*)&As[wm + i * 16 + lr][lk];
#pragma unroll
    for (int j = 0; j < 4; j++) b[j] = *(const short8*)&Bs[wn + j * 16 + lr][lk];
#pragma unroll
    for (int i = 0; i < 4; i++)
#pragma unroll
      for (int j = 0; j < 4; j++)
        acc[i][j] = mfma16((const short*)&a[i], (const short*)&b[j], acc[i][j]);
    __syncthreads();
  }

  int proj = blockIdx.y / 6;                 // 0=Q 1=K 2=V
  int nloc0 = n0 - proj * 768;
  int hhb = nloc0 >> 6;
  int b = m0 >> 10, s0v = m0 & 1023;

  if (proj < 2) {
    short* dst = (proj == 0) ? Qb : Kb;
    const float* bias = (proj == 0) ? bq : bk;
#pragma unroll
    for (int j = 0; j < 4; j++) {
      float bb = bias[nloc0 + wn + j * 16 + lr];
#pragma unroll
      for (int i = 0; i < 4; i++)
#pragma unroll
        for (int jj = 0; jj < 4; jj++)
          Cs[wm + i * 16 + (lane >> 4) * 4 + jj][wn + j * 16 + lr] = f2bf(acc[i][j][jj] + bb);
    }
    __syncthreads();
#pragma unroll
    for (int hh2 = 0; hh2 < 2; hh2++) {
      short* base = dst + ((size_t)(b * 12 + hhb + hh2) * 1024 + s0v) * 64;
#pragma unroll
      for (int u = 0; u < 4; u++) {
        int c = t + u * 256;
        int sl = c >> 3, dh0 = (c & 7) * 8;
        *(short8*)&base[(size_t)c * 8] = *(const short8*)&Cs[sl][hh2 * 64 + dh0];
      }
    }
  } else {
#pragma unroll
    for (int j = 0; j < 4; j++) {
      float bb = bv[nloc0 + wn + j * 16 + lr];
#pragma unroll
      for (int i = 0; i < 4; i++) {
        short4v p;
        p.x = f2bf(acc[i][j][0] + bb);
        p.y = f2bf(acc[i][j][1] + bb);
        p.z = f2bf(acc[i][j][2] + bb);
        p.w = f2bf(acc[i][j][3] + bb);
        *(short4v*)&Cs[wn + j * 16 + lr][wm + i * 16 + (lane >> 4) * 4] = p;
      }
    }
    __syncthreads();
#pragma unroll
    for (int u = 0; u < 8; u++) {
      int row = (t >> 4) + u * 16;
      int hh2 = row >> 6, dh = row & 63;
      *(short8*)&Vtb[((size_t)(b * 12 + hhb + hh2) * 64 + dh) * 1024 + s0v + (t & 15) * 8]
          = *(const short8*)&Cs[row][(t & 15) * 8];
    }
  }
}

// ---------------- fused attention v2: barrier-free, wave-owned rows ----------------
// grid 1536 (XCD-swizzled): block = (b,h, 64 q-rows); wave = 16 q-rows x full 1024 cols.
// 3 passes over K (max / sum / normalize+write+PV), wave-local softmax, chunked P via
// wave-private LDS (no __syncthreads anywhere).
__global__ __launch_bounds__(256) void attn_fused(const short* __restrict__ Qb,
                                                  const short* __restrict__ Kb,
                                                  const short* __restrict__ Vtb,
                                                  const int* __restrict__ amask,
                                                  float* __restrict__ probs,
                                                  short* __restrict__ ctxb) {
  __shared__ short Pw[4][16][136];   // wave-private 16x128 bf16 chunk (+pad)

  int orig = blockIdx.x;
  int wg = (orig & 7) * 192 + (orig >> 3);     // bijective XCD chunking (1536 % 8 == 0)
  int bh = wg >> 4, qt = wg & 15;
  int b = bh / 12, h = bh - b * 12;
  int t = threadIdx.x, w = t >> 6, lane = t & 63;
  int lr = lane & 15, lg = lane >> 4, lk = lg * 8;
  int q0 = qt * 64 + w * 16;

  const short* Qp = Qb + ((size_t)bh * 1024 + q0) * 64;
  const short* Kp = Kb + (size_t)bh * 65536;
  const short* Vp = Vtb + (size_t)bh * 65536;
  const int* mb = amask + b * 1024;

  short8 aq0 = *(const short8*)&Qp[lr * 64 + lk];
  short8 aq1 = *(const short8*)&Qp[lr * 64 + 32 + lk];

  // mask bitset: col = nt*16 + lr
  unsigned long long mbits = 0ull;
#pragma unroll 8
  for (int nt = 0; nt < 64; nt++)
    mbits |= (unsigned long long)(mb[nt * 16 + lr] != 0) << nt;

  // ---- pass 1: row max ----
  float mx[4] = {-1e30f, -1e30f, -1e30f, -1e30f};
#pragma unroll 4
  for (int nt = 0; nt < 64; nt++) {
    const short* kp = Kp + (size_t)(nt * 16 + lr) * 64;
    short8 b0 = *(const short8*)&kp[lk];
    short8 b1 = *(const short8*)&kp[32 + lk];
    float4v s4 = {};
    s4 = mfma16((const short*)&aq0, (const short*)&b0, s4);
    s4 = mfma16((const short*)&aq1, (const short*)&b1, s4);
    if ((mbits >> nt) & 1) {
#pragma unroll
      for (int j = 0; j < 4; j++) mx[j] = fmaxf(mx[j], s4[j] * 0.125f);
    }
  }
#pragma unroll
  for (int j = 0; j < 4; j++) {
#pragma unroll
    for (int off = 1; off < 16; off <<= 1) mx[j] = fmaxf(mx[j], __shfl_xor(mx[j], off));
  }

  // ---- pass 2: row sum of exp ----
  float sm[4] = {0.f, 0.f, 0.f, 0.f};
#pragma unroll 4
  for (int nt = 0; nt < 64; nt++) {
    const short* kp = Kp + (size_t)(nt * 16 + lr) * 64;
    short8 b0 = *(const short8*)&kp[lk];
    short8 b1 = *(const short8*)&kp[32 + lk];
    float4v s4 = {};
    s4 = mfma16((const short*)&aq0, (const short*)&b0, s4);
    s4 = mfma16((const short*)&aq1, (const short*)&b1, s4);
    if ((mbits >> nt) & 1) {
#pragma unroll
      for (int j = 0; j < 4; j++) sm[j] += __expf(s4[j] * 0.125f - mx[j]);
    }
  }
#pragma unroll
  for (int j = 0; j < 4; j++) {
#pragma unroll
    for (int off = 1; off < 16; off <<= 1) sm[j] += __shfl_xor(sm[j], off);
  }
  float inv[4];
#pragma unroll
  for (int j = 0; j < 4; j++) inv[j] = (sm[j] > 0.f) ? 1.f / sm[j] : 0.f;

  // ---- pass 3: normalize + probs write + PV, in 128-col chunks ----
  float4v c[4] = {};
  size_t pbase = ((size_t)bh * 1024 + q0) * 1024;
  for (int ch = 0; ch < 8; ch++) {
#pragma unroll 2
    for (int nt2 = 0; nt2 < 8; nt2++) {
      int nt = ch * 8 + nt2;
      const short* kp = Kp + (size_t)(nt * 16 + lr) * 64;
      short8 b0 = *(const short8*)&kp[lk];
      short8 b1 = *(const short8*)&kp[32 + lk];
      float4v s4 = {};
      s4 = mfma16((const short*)&aq0, (const short*)&b0, s4);
      s4 = mfma16((const short*)&aq1, (const short*)&b1, s4);
      bool live = (mbits >> nt) & 1;
#pragma unroll
      for (int j = 0; j < 4; j++) {
        float p = live ? __expf(s4[j] * 0.125f - mx[j]) * inv[j] : 0.f;
        Pw[w][lg * 4 + j][nt2 * 16 + lr] = f2bf(p);
      }
    }
    // probs write: 16 rows x 128 cols fp32, float4-coalesced
#pragma unroll
    for (int u = 0; u < 8; u++) {
      int slot = u * 64 + lane;
      int r = slot >> 5, c4 = (slot & 31) * 4;
      short4v pv = *(const short4v*)&Pw[w][r][c4];
      float4v f;
      f.x = bf2f(pv.x); f.y = bf2f(pv.y); f.z = bf2f(pv.z); f.w = bf2f(pv.w);
      *(float4v*)&probs[pbase + (size_t)r * 1024 + ch * 128 + c4] = f;
    }
    // PV over this chunk
#pragma unroll
    for (int ks = 0; ks < 4; ks++) {
      short8 ap = *(const short8*)&Pw[w][lr][ks * 32 + lk];
#pragma unroll
      for (int n2 = 0; n2 < 4; n2++) {
        short8 bvv = *(const short8*)&Vp[(size_t)(n2 * 16 + lr) * 1024 + ch * 128 + ks * 32 + lk];
        c[n2] = mfma16((const short*)&ap, (const short*)&bvv, c[n2]);
      }
    }
  }

  // ---- ctx epilogue: bounce through wave-private LDS, vector store ----
  float (*cw)[68] = (float(*)[68])&Pw[w][0][0];
#pragma unroll
  for (int n2 = 0; n2 < 4; n2++)
#pragma unroll
    for (int j = 0; j < 4; j++)
      cw[lg * 4 + j][n2 * 16 + lr] = c[n2][j];
#pragma unroll
  for (int u = 0; u < 2; u++) {
    int idx = u * 64 + lane;
    int r = idx >> 3, g = idx & 7;
    const float* src = &cw[r][g * 8];
    short8 o;
    o[0] = f2bf(src[0]); o[1] = f2bf(src[1]); o[2] = f2bf(src[2]); o[3] = f2bf(src[3]);
    o[4] = f2bf(src[4]); o[5] = f2bf(src[5]); o[6] = f2bf(src[6]); o[7] = f2bf(src[7]);
    *(short8*)&ctxb[((size_t)(b * 1024 + q0 + r)) * 768 + h * 64 + g * 8] = o;
  }
}

// ---------------- O projection (NT) + bias + residual -> h fp32 ----------------
__global__ __launch_bounds__(256) void gemm_o(const short* __restrict__ A,
                                              const short* __restrict__ Bw,
                                              const float* __restrict__ bo,
                                              const float* __restrict__ hidden,
                                              float* __restrict__ hout) {
  __shared__ short As[128][32];
  __shared__ short Bs[128][32];
  int m0 = blockIdx.x * 128, n0 = blockIdx.y * 128;
  int t = threadIdx.x, w = t >> 6, lane = t & 63;
  int wm = (w >> 1) * 64, wn = (w & 1) * 64;
  int lr = lane & 15, lk = (lane >> 4) * 8;

  const short* gA = A + (size_t)(m0 + w * 32 + (lane >> 2)) * 768 + (lane & 3) * 8;
  const short* gB = Bw + (size_t)(n0 + w * 32 + (lane >> 2)) * 768 + (lane & 3) * 8;

  float4v acc[4][4] = {};

  for (int k0 = 0; k0 < 768; k0 += 32) {
    gload16(gA, &As[w * 32][0]);
    gload16(gA + 16 * 768, &As[w * 32 + 16][0]);
    gload16(gB, &Bs[w * 32][0]);
    gload16(gB + 16 * 768, &Bs[w * 32 + 16][0]);
    gA += 32; gB += 32;
    __syncthreads();
    short8 a[4], b[4];
#pragma unroll
    for (int i = 0; i < 4; i++) a[i] = *(const short8*)&As[wm + i * 16 + lr][lk];
#pragma unroll
    for (int j = 0; j < 4; j++) b[j] = *(const short8*)&Bs[wn + j * 16 + lr][lk];
#pragma unroll
    for (int i = 0; i < 4; i++)
#pragma unroll
      for (int j = 0; j < 4; j++)
        acc[i][j] = mfma16((const short*)&a[i], (const short*)&b[j], acc[i][j]);
    __syncthreads();
  }

#pragma unroll
  for (int j = 0; j < 4; j++) {
    int gn = n0 + wn + j * 16 + lr;
    float bb = bo[gn];
#pragma unroll
    for (int i = 0; i < 4; i++) {
      int gm0 = m0 + wm + i * 16 + ((lane >> 4) << 2);
#pragma unroll
      for (int jj = 0; jj < 4; jj++) {
        int r = gm0 + jj;
        size_t idx = (size_t)r * 768 + gn;
        hout[idx] = acc[i][j][jj] + bb + hidden[idx];
      }
    }
  }
}

// ---------------- LayerNorm over D=768 ----------------
__global__ __launch_bounds__(256) void lnorm(const float* __restrict__ h,
                                             const float* __restrict__ g,
                                             const float* __restrict__ be,
                                             float* __restrict__ out) {
  int row = blockIdx.x;
  const float* x = h + (size_t)row * 768;
  int t = threadIdx.x;
  float v0 = x[t], v1 = x[t + 256], v2 = x[t + 512];
  float s = v0 + v1 + v2;
#pragma unroll
  for (int off = 1; off < 64; off <<= 1) s += __shfl_xor(s, off);
  __shared__ float r1[4], r2[4];
  if ((t & 63) == 0) r1[t >> 6] = s;
  __syncthreads();
  float mean = (r1[0] + r1[1] + r1[2] + r1[3]) * (1.f / 768.f);
  float d0 = v0 - mean, d1 = v1 - mean, d2 = v2 - mean;
  float q = d0 * d0 + d1 * d1 + d2 * d2;
#pragma unroll
  for (int off = 1; off < 64; off <<= 1) q += __shfl_xor(q, off);
  if ((t & 63) == 0) r2[t >> 6] = q;
  __syncthreads();
  float var = (r2[0] + r2[1] + r2[2] + r2[3]) * (1.f / 768.f);
  float rr = rsqrtf(var + 1e-12f);
  size_t o = (size_t)row * 768;
  out[o + t]       = d0 * rr * g[t] + be[t];
  out[o + t + 256] = d1 * rr * g[t + 256] + be[t + 256];
  out[o + t + 512] = d2 * rr * g[t + 512] + be[t + 512];
}

extern "C" void kernel_launch(void* const* d_in, const int* in_sizes, int n_in,
                              void* d_out, int out_size, void* d_ws, size_t ws_size,
                              hipStream_t stream) {
  const float* hs    = (const float*)d_in[0];
  const int*   amask = (const int*)d_in[1];
  const float* Wq    = (const float*)d_in[2];
  const float* bq    = (const float*)d_in[3];
  const float* Wk    = (const float*)d_in[4];
  const float* bk    = (const float*)d_in[5];
  const float* Wv    = (const float*)d_in[6];
  const float* bv    = (const float*)d_in[7];
  const float* Wo    = (const float*)d_in[8];
  const float* bo    = (const float*)d_in[9];
  const float* lng   = (const float*)d_in[10];
  const float* lnb   = (const float*)d_in[11];

  char* wsp = (char*)d_ws;
  const size_t NTOK = (size_t)B_ * S_;  // 8192
  short* hsb  = (short*)wsp; wsp += NTOK * D_ * 2;
  short* wqkv = (short*)wsp; wsp += (size_t)3 * D_ * D_ * 2;
  short* wob  = (short*)wsp; wsp += (size_t)D_ * D_ * 2;
  short* Qb   = (short*)wsp; wsp += NTOK * D_ * 2;
  short* Kb   = (short*)wsp; wsp += NTOK * D_ * 2;
  short* Vtb  = (short*)wsp; wsp += NTOK * D_ * 2;
  short* ctxb = (short*)wsp; wsp += NTOK * D_ * 2;
  float* hbuf = (float*)wsp; wsp += NTOK * D_ * 4;

  float* out   = (float*)d_out;
  float* probs = out + NTOK * D_;

  int n4hs = (int)(NTOK * D_ / 4);
  cvt_bf16<<<dim3((n4hs + 255) / 256), dim3(256), 0, stream>>>(hs, hsb, n4hs);
  cvt_w4<<<dim3(4 * 576), dim3(256), 0, stream>>>(Wq, Wk, Wv, Wo, wqkv, wob);

  gemm_qkv<<<dim3(64, 18), dim3(256), 0, stream>>>(hsb, wqkv, bq, bk, bv, Qb, Kb, Vtb);
  attn_fused<<<dim3(1536), dim3(256), 0, stream>>>(Qb, Kb, Vtb, amask, probs, ctxb);
  gemm_o<<<dim3(64, 6), dim3(256), 0, stream>>>(ctxb, wob, bo, hs, hbuf);
  lnorm<<<dim3(8192), dim3(256), 0, stream>>>(hbuf, lng, lnb, out);
}

// Round 6
// 718.572 us; speedup vs baseline: 1.2963x; 1.2963x over previous
//
#include <hip/hip_runtime.h>

#define B_ 8
#define S_ 1024
#define D_ 768
#define H_ 12
#define DH_ 64

typedef __attribute__((ext_vector_type(8))) short short8;
typedef __attribute__((ext_vector_type(4))) short short4v;
typedef __attribute__((ext_vector_type(4))) float float4v;
typedef __attribute__((ext_vector_type(8))) __bf16 bf16x8;

static __device__ __forceinline__ short f2bf(float f) {
  union { float f; unsigned u; } v; v.f = f;
  unsigned r = v.u + 0x7fffu + ((v.u >> 16) & 1u);
  return (short)(r >> 16);
}
static __device__ __forceinline__ float bf2f(short s) {
  union { unsigned u; float f; } v; v.u = ((unsigned)(unsigned short)s) << 16;
  return v.f;
}

static __device__ __forceinline__ float4v mfma16(const short* ap, const short* bp, float4v c) {
  bf16x8 a = *(const bf16x8*)ap;
  bf16x8 b = *(const bf16x8*)bp;
  return __builtin_amdgcn_mfma_f32_16x16x32_bf16(a, b, c, 0, 0, 0);
}

typedef const __attribute__((address_space(1))) unsigned gu32;
typedef __attribute__((address_space(3))) unsigned lu32;
static __device__ __forceinline__ void gload16(const void* g, void* l) {
  __builtin_amdgcn_global_load_lds((gu32*)g, (lu32*)l, 16, 0, 0);
}

// ---------------- fp32 -> bf16 conversion (hidden states) ----------------
__global__ __launch_bounds__(256) void cvt_bf16(const float* __restrict__ src,
                                                short* __restrict__ dst, int n4) {
  int i = blockIdx.x * 256 + threadIdx.x;
  if (i < n4) {
    float4v v = ((const float4v*)src)[i];
    short4v o;
    o.x = f2bf(v.x); o.y = f2bf(v.y); o.z = f2bf(v.z); o.w = f2bf(v.w);
    ((short4v*)dst)[i] = o;
  }
}

// ---------------- all 4 weight matrices in one launch ----------------
__global__ __launch_bounds__(256) void cvt_w4(const float* __restrict__ w0,
                                              const float* __restrict__ w1,
                                              const float* __restrict__ w2,
                                              const float* __restrict__ w3,
                                              short* __restrict__ wqkv,
                                              short* __restrict__ wob) {
  int seg = blockIdx.x / 576, loc = blockIdx.x % 576;
  const float* src = (seg == 0) ? w0 : (seg == 1) ? w1 : (seg == 2) ? w2 : w3;
  short* dst = (seg < 3) ? (wqkv + (size_t)seg * 589824) : wob;
  int i = loc * 256 + threadIdx.x;
  float4v v = ((const float4v*)src)[i];
  short4v o;
  o.x = f2bf(v.x); o.y = f2bf(v.y); o.z = f2bf(v.z); o.w = f2bf(v.w);
  ((short4v*)dst)[i] = o;
}

// ---------------- QKV projection GEMM (NT): C[8192][2304] = hs_bf16 @ Wqkv^T ----------------
__global__ __launch_bounds__(256) void gemm_qkv(const short* __restrict__ A,
                                                const short* __restrict__ Bw,
                                                const float* __restrict__ bq,
                                                const float* __restrict__ bk,
                                                const float* __restrict__ bv,
                                                short* __restrict__ Qb,
                                                short* __restrict__ Kb,
                                                short* __restrict__ Vtb) {
  __shared__ char smem[34816];                       // Cs[128][136] overlay; As+Bs = 16KB
  short (*As)[32] = (short(*)[32])smem;
  short (*Bs)[32] = (short(*)[32])(smem + 8192);
  short (*Cs)[136] = (short(*)[136])smem;

  int m0 = blockIdx.x * 128, n0 = blockIdx.y * 128;
  int t = threadIdx.x, w = t >> 6, lane = t & 63;
  int wm = (w >> 1) * 64, wn = (w & 1) * 64;
  int lr = lane & 15, lk = (lane >> 4) * 8;

  const short* gA = A + (size_t)(m0 + w * 32 + (lane >> 2)) * 768 + (lane & 3) * 8;
  const short* gB = Bw + (size_t)(n0 + w * 32 + (lane >> 2)) * 768 + (lane & 3) * 8;

  float4v acc[4][4] = {};

  for (int k0 = 0; k0 < 768; k0 += 32) {
    gload16(gA, &As[w * 32][0]);
    gload16(gA + 16 * 768, &As[w * 32 + 16][0]);
    gload16(gB, &Bs[w * 32][0]);
    gload16(gB + 16 * 768, &Bs[w * 32 + 16][0]);
    gA += 32; gB += 32;
    __syncthreads();
    short8 a[4], b[4];
#pragma unroll
    for (int i = 0; i < 4; i++) a[i] = *(const short8*)&As[wm + i * 16 + lr][lk];
#pragma unroll
    for (int j = 0; j < 4; j++) b[j] = *(const short8*)&Bs[wn + j * 16 + lr][lk];
#pragma unroll
    for (int i = 0; i < 4; i++)
#pragma unroll
      for (int j = 0; j < 4; j++)
        acc[i][j] = mfma16((const short*)&a[i], (const short*)&b[j], acc[i][j]);
    __syncthreads();
  }

  int proj = blockIdx.y / 6;                 // 0=Q 1=K 2=V
  int nloc0 = n0 - proj * 768;
  int hhb = nloc0 >> 6;
  int b = m0 >> 10, s0v = m0 & 1023;

  if (proj < 2) {
    short* dst = (proj == 0) ? Qb : Kb;
    const float* bias = (proj == 0) ? bq : bk;
#pragma unroll
    for (int j = 0; j < 4; j++) {
      float bb = bias[nloc0 + wn + j * 16 + lr];
#pragma unroll
      for (int i = 0; i < 4; i++)
#pragma unroll
        for (int jj = 0; jj < 4; jj++)
          Cs[wm + i * 16 + (lane >> 4) * 4 + jj][wn + j * 16 + lr] = f2bf(acc[i][j][jj] + bb);
    }
    __syncthreads();
#pragma unroll
    for (int hh2 = 0; hh2 < 2; hh2++) {
      short* base = dst + ((size_t)(b * 12 + hhb + hh2) * 1024 + s0v) * 64;
#pragma unroll
      for (int u = 0; u < 4; u++) {
        int c = t + u * 256;
        int sl = c >> 3, dh0 = (c & 7) * 8;
        *(short8*)&base[(size_t)c * 8] = *(const short8*)&Cs[sl][hh2 * 64 + dh0];
      }
    }
  } else {
#pragma unroll
    for (int j = 0; j < 4; j++) {
      float bb = bv[nloc0 + wn + j * 16 + lr];
#pragma unroll
      for (int i = 0; i < 4; i++) {
        short4v p;
        p.x = f2bf(acc[i][j][0] + bb);
        p.y = f2bf(acc[i][j][1] + bb);
        p.z = f2bf(acc[i][j][2] + bb);
        p.w = f2bf(acc[i][j][3] + bb);
        *(short4v*)&Cs[wn + j * 16 + lr][wm + i * 16 + (lane >> 4) * 4] = p;
      }
    }
    __syncthreads();
#pragma unroll
    for (int u = 0; u < 8; u++) {
      int row = (t >> 4) + u * 16;
      int hh2 = row >> 6, dh = row & 63;
      *(short8*)&Vtb[((size_t)(b * 12 + hhb + hh2) * 64 + dh) * 1024 + s0v + (t & 15) * 8]
          = *(const short8*)&Cs[row][(t & 15) * 8];
    }
  }
}

// ---------------- fused attention v3: 16-row q-tile per block, scores in regs ----------------
// 4 waves x 256 cols each; single QK^T pass; LDS-reduced softmax (2 barriers);
// coalesced float4 probs write; PV dh-split across waves (no cross-wave reduction).
__global__ __launch_bounds__(256) void attn_fused(const short* __restrict__ Qb,
                                                  const short* __restrict__ Kb,
                                                  const short* __restrict__ Vtb,
                                                  const int* __restrict__ amask,
                                                  float* __restrict__ probs,
                                                  short* __restrict__ ctxb) {
  __shared__ short P[16][1032];       // 33.0 KB bf16 probs tile
  __shared__ float ctxf[16][68];      // 4.4 KB ctx bounce
  __shared__ float redmax[4][16];
  __shared__ float redsum[4][16];

  int qt = blockIdx.x, bh = blockIdx.y;
  int b = bh / 12, h = bh - b * 12;
  int q0 = qt * 16;
  const short* Qp = Qb + ((size_t)bh * 1024 + q0) * 64;
  const short* Kp = Kb + (size_t)bh * 65536;
  const short* Vp = Vtb + (size_t)bh * 65536;
  const int* mb = amask + b * 1024;

  int t = threadIdx.x, w = t >> 6, lane = t & 63;
  int lr = lane & 15, lg = lane >> 4, lk = lg * 8;

  short8 aq0 = *(const short8*)&Qp[lr * 64 + lk];
  short8 aq1 = *(const short8*)&Qp[lr * 64 + 32 + lk];

  // ---- single QK^T pass: wave w owns cols [w*256, w*256+256), scores in regs ----
  float4v acc[16] = {};
#pragma unroll
  for (int nt = 0; nt < 16; nt++) {
    const short* kp = Kp + (size_t)(w * 256 + nt * 16 + lr) * 64;
    short8 b0 = *(const short8*)&kp[lk];
    short8 b1 = *(const short8*)&kp[32 + lk];
    acc[nt] = mfma16((const short*)&aq0, (const short*)&b0, acc[nt]);
    acc[nt] = mfma16((const short*)&aq1, (const short*)&b1, acc[nt]);
  }

  unsigned mbits = 0;
#pragma unroll
  for (int nt = 0; nt < 16; nt++)
    mbits |= (mb[w * 256 + nt * 16 + lr] != 0 ? 1u : 0u) << nt;

  // ---- row max (rows r = lg*4 + j) ----
  float mx[4] = {-1e30f, -1e30f, -1e30f, -1e30f};
#pragma unroll
  for (int nt = 0; nt < 16; nt++)
#pragma unroll
    for (int j = 0; j < 4; j++) {
      float s = acc[nt][j] * 0.125f;
      if (!((mbits >> nt) & 1)) s = -1e30f;
      acc[nt][j] = s;
      mx[j] = fmaxf(mx[j], s);
    }
#pragma unroll
  for (int j = 0; j < 4; j++) {
#pragma unroll
    for (int off = 1; off < 16; off <<= 1) mx[j] = fmaxf(mx[j], __shfl_xor(mx[j], off));
  }
  if (lr == 0) {
#pragma unroll
    for (int j = 0; j < 4; j++) redmax[w][lg * 4 + j] = mx[j];
  }
  __syncthreads();
  float gmx[4];
#pragma unroll
  for (int j = 0; j < 4; j++) {
    int r = lg * 4 + j;
    gmx[j] = fmaxf(fmaxf(redmax[0][r], redmax[1][r]), fmaxf(redmax[2][r], redmax[3][r]));
  }

  // ---- exp + row sum ----
  float sm[4] = {0.f, 0.f, 0.f, 0.f};
#pragma unroll
  for (int nt = 0; nt < 16; nt++)
#pragma unroll
    for (int j = 0; j < 4; j++) {
      float p = ((mbits >> nt) & 1) ? __expf(acc[nt][j] - gmx[j]) : 0.f;
      acc[nt][j] = p;
      sm[j] += p;
    }
#pragma unroll
  for (int j = 0; j < 4; j++) {
#pragma unroll
    for (int off = 1; off < 16; off <<= 1) sm[j] += __shfl_xor(sm[j], off);
  }
  if (lr == 0) {
#pragma unroll
    for (int j = 0; j < 4; j++) redsum[w][lg * 4 + j] = sm[j];
  }
  __syncthreads();
  float inv[4];
#pragma unroll
  for (int j = 0; j < 4; j++) {
    int r = lg * 4 + j;
    float s = redsum[0][r] + redsum[1][r] + redsum[2][r] + redsum[3][r];
    inv[j] = (s > 0.f) ? 1.f / s : 0.f;
  }

  // ---- normalize -> P (bf16 LDS) ----
#pragma unroll
  for (int nt = 0; nt < 16; nt++) {
    int col = w * 256 + nt * 16 + lr;
#pragma unroll
    for (int j = 0; j < 4; j++)
      P[lg * 4 + j][col] = f2bf(acc[nt][j] * inv[j]);
  }
  __syncthreads();

  // ---- probs write: coalesced float4 from P ----
  size_t pbase = ((size_t)bh * 1024 + q0) * 1024;
  {
    int prow = t >> 4;
    int cb = (t & 15) * 4;
    float* orow = probs + pbase + (size_t)prow * 1024;
#pragma unroll
    for (int u = 0; u < 16; u++) {
      int col = cb + u * 64;
      short4v pv = *(const short4v*)&P[prow][col];
      float4v f;
      f.x = bf2f(pv.x); f.y = bf2f(pv.y); f.z = bf2f(pv.z); f.w = bf2f(pv.w);
      *(float4v*)&orow[col] = f;
    }
  }

  // ---- PV dh-split: wave w computes dh in [w*16, w*16+16) over all 1024 k ----
  float4v c0 = {}, c1 = {};
  const short* vrow = Vp + (size_t)(w * 16 + lr) * 1024;
#pragma unroll
  for (int kk = 0; kk < 32; kk += 2) {
    short8 ap0 = *(const short8*)&P[lr][kk * 32 + lk];
    short8 bv0 = *(const short8*)&vrow[kk * 32 + lk];
    c0 = mfma16((const short*)&ap0, (const short*)&bv0, c0);
    short8 ap1 = *(const short8*)&P[lr][(kk + 1) * 32 + lk];
    short8 bv1 = *(const short8*)&vrow[(kk + 1) * 32 + lk];
    c1 = mfma16((const short*)&ap1, (const short*)&bv1, c1);
  }
  c0 = c0 + c1;
#pragma unroll
  for (int j = 0; j < 4; j++)
    ctxf[lg * 4 + j][w * 16 + lr] = c0[j];
  __syncthreads();

  // ---- ctx store: 16 rows x 64 dh, short8 vector stores ----
  if (t < 128) {
    int row = t >> 3, g = t & 7;
    const float* src = &ctxf[row][g * 8];
    short8 o;
    o[0] = f2bf(src[0]); o[1] = f2bf(src[1]); o[2] = f2bf(src[2]); o[3] = f2bf(src[3]);
    o[4] = f2bf(src[4]); o[5] = f2bf(src[5]); o[6] = f2bf(src[6]); o[7] = f2bf(src[7]);
    *(short8*)&ctxb[((size_t)(b * 1024 + q0 + row)) * 768 + h * 64 + g * 8] = o;
  }
}

// ---------------- O projection (NT) + bias + residual -> h fp32 ----------------
__global__ __launch_bounds__(256) void gemm_o(const short* __restrict__ A,
                                              const short* __restrict__ Bw,
                                              const float* __restrict__ bo,
                                              const float* __restrict__ hidden,
                                              float* __restrict__ hout) {
  __shared__ short As[128][32];
  __shared__ short Bs[128][32];
  int m0 = blockIdx.x * 128, n0 = blockIdx.y * 128;
  int t = threadIdx.x, w = t >> 6, lane = t & 63;
  int wm = (w >> 1) * 64, wn = (w & 1) * 64;
  int lr = lane & 15, lk = (lane >> 4) * 8;

  const short* gA = A + (size_t)(m0 + w * 32 + (lane >> 2)) * 768 + (lane & 3) * 8;
  const short* gB = Bw + (size_t)(n0 + w * 32 + (lane >> 2)) * 768 + (lane & 3) * 8;

  float4v acc[4][4] = {};

  for (int k0 = 0; k0 < 768; k0 += 32) {
    gload16(gA, &As[w * 32][0]);
    gload16(gA + 16 * 768, &As[w * 32 + 16][0]);
    gload16(gB, &Bs[w * 32][0]);
    gload16(gB + 16 * 768, &Bs[w * 32 + 16][0]);
    gA += 32; gB += 32;
    __syncthreads();
    short8 a[4], b[4];
#pragma unroll
    for (int i = 0; i < 4; i++) a[i] = *(const short8*)&As[wm + i * 16 + lr][lk];
#pragma unroll
    for (int j = 0; j < 4; j++) b[j] = *(const short8*)&Bs[wn + j * 16 + lr][lk];
#pragma unroll
    for (int i = 0; i < 4; i++)
#pragma unroll
      for (int j = 0; j < 4; j++)
        acc[i][j] = mfma16((const short*)&a[i], (const short*)&b[j], acc[i][j]);
    __syncthreads();
  }

#pragma unroll
  for (int j = 0; j < 4; j++) {
    int gn = n0 + wn + j * 16 + lr;
    float bb = bo[gn];
#pragma unroll
    for (int i = 0; i < 4; i++) {
      int gm0 = m0 + wm + i * 16 + ((lane >> 4) << 2);
#pragma unroll
      for (int jj = 0; jj < 4; jj++) {
        int r = gm0 + jj;
        size_t idx = (size_t)r * 768 + gn;
        hout[idx] = acc[i][j][jj] + bb + hidden[idx];
      }
    }
  }
}

// ---------------- LayerNorm over D=768 ----------------
__global__ __launch_bounds__(256) void lnorm(const float* __restrict__ h,
                                             const float* __restrict__ g,
                                             const float* __restrict__ be,
                                             float* __restrict__ out) {
  int row = blockIdx.x;
  const float* x = h + (size_t)row * 768;
  int t = threadIdx.x;
  float v0 = x[t], v1 = x[t + 256], v2 = x[t + 512];
  float s = v0 + v1 + v2;
#pragma unroll
  for (int off = 1; off < 64; off <<= 1) s += __shfl_xor(s, off);
  __shared__ float r1[4], r2[4];
  if ((t & 63) == 0) r1[t >> 6] = s;
  __syncthreads();
  float mean = (r1[0] + r1[1] + r1[2] + r1[3]) * (1.f / 768.f);
  float d0 = v0 - mean, d1 = v1 - mean, d2 = v2 - mean;
  float q = d0 * d0 + d1 * d1 + d2 * d2;
#pragma unroll
  for (int off = 1; off < 64; off <<= 1) q += __shfl_xor(q, off);
  if ((t & 63) == 0) r2[t >> 6] = q;
  __syncthreads();
  float var = (r2[0] + r2[1] + r2[2] + r2[3]) * (1.f / 768.f);
  float rr = rsqrtf(var + 1e-12f);
  size_t o = (size_t)row * 768;
  out[o + t]       = d0 * rr * g[t] + be[t];
  out[o + t + 256] = d1 * rr * g[t + 256] + be[t + 256];
  out[o + t + 512] = d2 * rr * g[t + 512] + be[t + 512];
}

extern "C" void kernel_launch(void* const* d_in, const int* in_sizes, int n_in,
                              void* d_out, int out_size, void* d_ws, size_t ws_size,
                              hipStream_t stream) {
  const float* hs    = (const float*)d_in[0];
  const int*   amask = (const int*)d_in[1];
  const float* Wq    = (const float*)d_in[2];
  const float* bq    = (const float*)d_in[3];
  const float* Wk    = (const float*)d_in[4];
  const float* bk    = (const float*)d_in[5];
  const float* Wv    = (const float*)d_in[6];
  const float* bv    = (const float*)d_in[7];
  const float* Wo    = (const float*)d_in[8];
  const float* bo    = (const float*)d_in[9];
  const float* lng   = (const float*)d_in[10];
  const float* lnb   = (const float*)d_in[11];

  char* wsp = (char*)d_ws;
  const size_t NTOK = (size_t)B_ * S_;  // 8192
  short* hsb  = (short*)wsp; wsp += NTOK * D_ * 2;
  short* wqkv = (short*)wsp; wsp += (size_t)3 * D_ * D_ * 2;
  short* wob  = (short*)wsp; wsp += (size_t)D_ * D_ * 2;
  short* Qb   = (short*)wsp; wsp += NTOK * D_ * 2;
  short* Kb   = (short*)wsp; wsp += NTOK * D_ * 2;
  short* Vtb  = (short*)wsp; wsp += NTOK * D_ * 2;
  short* ctxb = (short*)wsp; wsp += NTOK * D_ * 2;
  float* hbuf = (float*)wsp; wsp += NTOK * D_ * 4;

  float* out   = (float*)d_out;
  float* probs = out + NTOK * D_;

  int n4hs = (int)(NTOK * D_ / 4);
  cvt_bf16<<<dim3((n4hs + 255) / 256), dim3(256), 0, stream>>>(hs, hsb, n4hs);
  cvt_w4<<<dim3(4 * 576), dim3(256), 0, stream>>>(Wq, Wk, Wv, Wo, wqkv, wob);

  gemm_qkv<<<dim3(64, 18), dim3(256), 0, stream>>>(hsb, wqkv, bq, bk, bv, Qb, Kb, Vtb);
  attn_fused<<<dim3(64, 96), dim3(256), 0, stream>>>(Qb, Kb, Vtb, amask, probs, ctxb);
  gemm_o<<<dim3(64, 6), dim3(256), 0, stream>>>(ctxb, wob, bo, hs, hbuf);
  lnorm<<<dim3(8192), dim3(256), 0, stream>>>(hbuf, lng, lnb, out);
}

// Round 7
// 680.362 us; speedup vs baseline: 1.3691x; 1.0562x over previous
//
#include <hip/hip_runtime.h>

#define B_ 8
#define S_ 1024
#define D_ 768
#define H_ 12
#define DH_ 64

typedef __attribute__((ext_vector_type(8))) short short8;
typedef __attribute__((ext_vector_type(4))) short short4v;
typedef __attribute__((ext_vector_type(4))) float float4v;
typedef __attribute__((ext_vector_type(8))) __bf16 bf16x8;

static __device__ __forceinline__ short f2bf(float f) {
  union { float f; unsigned u; } v; v.f = f;
  unsigned r = v.u + 0x7fffu + ((v.u >> 16) & 1u);
  return (short)(r >> 16);
}
static __device__ __forceinline__ float bf2f(short s) {
  union { unsigned u; float f; } v; v.u = ((unsigned)(unsigned short)s) << 16;
  return v.f;
}

static __device__ __forceinline__ float4v mfma16(const short* ap, const short* bp, float4v c) {
  bf16x8 a = *(const bf16x8*)ap;
  bf16x8 b = *(const bf16x8*)bp;
  return __builtin_amdgcn_mfma_f32_16x16x32_bf16(a, b, c, 0, 0, 0);
}

typedef const __attribute__((address_space(1))) unsigned gu32;
typedef __attribute__((address_space(3))) unsigned lu32;
static __device__ __forceinline__ void gload16(const void* g, void* l) {
  __builtin_amdgcn_global_load_lds((gu32*)g, (lu32*)l, 16, 0, 0);
}

// ---------------- fp32 -> bf16 conversion (hidden states) ----------------
__global__ __launch_bounds__(256) void cvt_bf16(const float* __restrict__ src,
                                                short* __restrict__ dst, int n4) {
  int i = blockIdx.x * 256 + threadIdx.x;
  if (i < n4) {
    float4v v = ((const float4v*)src)[i];
    short4v o;
    o.x = f2bf(v.x); o.y = f2bf(v.y); o.z = f2bf(v.z); o.w = f2bf(v.w);
    ((short4v*)dst)[i] = o;
  }
}

// ---------------- all 4 weight matrices in one launch ----------------
__global__ __launch_bounds__(256) void cvt_w4(const float* __restrict__ w0,
                                              const float* __restrict__ w1,
                                              const float* __restrict__ w2,
                                              const float* __restrict__ w3,
                                              short* __restrict__ wqkv,
                                              short* __restrict__ wob) {
  int seg = blockIdx.x / 576, loc = blockIdx.x % 576;
  const float* src = (seg == 0) ? w0 : (seg == 1) ? w1 : (seg == 2) ? w2 : w3;
  short* dst = (seg < 3) ? (wqkv + (size_t)seg * 589824) : wob;
  int i = loc * 256 + threadIdx.x;
  float4v v = ((const float4v*)src)[i];
  short4v o;
  o.x = f2bf(v.x); o.y = f2bf(v.y); o.z = f2bf(v.z); o.w = f2bf(v.w);
  ((short4v*)dst)[i] = o;
}

// ---------------- QKV projection GEMM (NT): C[8192][2304] = hs_bf16 @ Wqkv^T ----------------
__global__ __launch_bounds__(256) void gemm_qkv(const short* __restrict__ A,
                                                const short* __restrict__ Bw,
                                                const float* __restrict__ bq,
                                                const float* __restrict__ bk,
                                                const float* __restrict__ bv,
                                                short* __restrict__ Qb,
                                                short* __restrict__ Kb,
                                                short* __restrict__ Vtb) {
  __shared__ char smem[34816];                       // Cs[128][136] overlay; As+Bs = 16KB
  short (*As)[32] = (short(*)[32])smem;
  short (*Bs)[32] = (short(*)[32])(smem + 8192);
  short (*Cs)[136] = (short(*)[136])smem;

  int m0 = blockIdx.x * 128, n0 = blockIdx.y * 128;
  int t = threadIdx.x, w = t >> 6, lane = t & 63;
  int wm = (w >> 1) * 64, wn = (w & 1) * 64;
  int lr = lane & 15, lk = (lane >> 4) * 8;

  const short* gA = A + (size_t)(m0 + w * 32 + (lane >> 2)) * 768 + (lane & 3) * 8;
  const short* gB = Bw + (size_t)(n0 + w * 32 + (lane >> 2)) * 768 + (lane & 3) * 8;

  float4v acc[4][4] = {};

  for (int k0 = 0; k0 < 768; k0 += 32) {
    gload16(gA, &As[w * 32][0]);
    gload16(gA + 16 * 768, &As[w * 32 + 16][0]);
    gload16(gB, &Bs[w * 32][0]);
    gload16(gB + 16 * 768, &Bs[w * 32 + 16][0]);
    gA += 32; gB += 32;
    __syncthreads();
    short8 a[4], b[4];
#pragma unroll
    for (int i = 0; i < 4; i++) a[i] = *(const short8*)&As[wm + i * 16 + lr][lk];
#pragma unroll
    for (int j = 0; j < 4; j++) b[j] = *(const short8*)&Bs[wn + j * 16 + lr][lk];
#pragma unroll
    for (int i = 0; i < 4; i++)
#pragma unroll
      for (int j = 0; j < 4; j++)
        acc[i][j] = mfma16((const short*)&a[i], (const short*)&b[j], acc[i][j]);
    __syncthreads();
  }

  int proj = blockIdx.y / 6;                 // 0=Q 1=K 2=V
  int nloc0 = n0 - proj * 768;
  int hhb = nloc0 >> 6;
  int b = m0 >> 10, s0v = m0 & 1023;

  if (proj < 2) {
    short* dst = (proj == 0) ? Qb : Kb;
    const float* bias = (proj == 0) ? bq : bk;
#pragma unroll
    for (int j = 0; j < 4; j++) {
      float bb = bias[nloc0 + wn + j * 16 + lr];
#pragma unroll
      for (int i = 0; i < 4; i++)
#pragma unroll
        for (int jj = 0; jj < 4; jj++)
          Cs[wm + i * 16 + (lane >> 4) * 4 + jj][wn + j * 16 + lr] = f2bf(acc[i][j][jj] + bb);
    }
    __syncthreads();
#pragma unroll
    for (int hh2 = 0; hh2 < 2; hh2++) {
      short* base = dst + ((size_t)(b * 12 + hhb + hh2) * 1024 + s0v) * 64;
#pragma unroll
      for (int u = 0; u < 4; u++) {
        int c = t + u * 256;
        int sl = c >> 3, dh0 = (c & 7) * 8;
        *(short8*)&base[(size_t)c * 8] = *(const short8*)&Cs[sl][hh2 * 64 + dh0];
      }
    }
  } else {
#pragma unroll
    for (int j = 0; j < 4; j++) {
      float bb = bv[nloc0 + wn + j * 16 + lr];
#pragma unroll
      for (int i = 0; i < 4; i++) {
        short4v p;
        p.x = f2bf(acc[i][j][0] + bb);
        p.y = f2bf(acc[i][j][1] + bb);
        p.z = f2bf(acc[i][j][2] + bb);
        p.w = f2bf(acc[i][j][3] + bb);
        *(short4v*)&Cs[wn + j * 16 + lr][wm + i * 16 + (lane >> 4) * 4] = p;
      }
    }
    __syncthreads();
#pragma unroll
    for (int u = 0; u < 8; u++) {
      int row = (t >> 4) + u * 16;
      int hh2 = row >> 6, dh = row & 63;
      *(short8*)&Vtb[((size_t)(b * 12 + hhb + hh2) * 64 + dh) * 1024 + s0v + (t & 15) * 8]
          = *(const short8*)&Cs[row][(t & 15) * 8];
    }
  }
}

// ---------------- fused attention v4: v3 + XCD chunking + nontemporal probs ----------------
// grid 6144 (1-D): g = (bid&7)*768 + bid>>3 -> each XCD owns 12 consecutive (b,h) heads,
// so K/V (256KB/head) stay L2-resident; probs stream written nontemporally to avoid
// evicting them.
__global__ __launch_bounds__(256) void attn_fused(const short* __restrict__ Qb,
                                                  const short* __restrict__ Kb,
                                                  const short* __restrict__ Vtb,
                                                  const int* __restrict__ amask,
                                                  float* __restrict__ probs,
                                                  short* __restrict__ ctxb) {
  __shared__ short P[16][1032];       // 33.0 KB bf16 probs tile
  __shared__ float ctxf[16][68];      // 4.4 KB ctx bounce
  __shared__ float redmax[4][16];
  __shared__ float redsum[4][16];

  int orig = blockIdx.x;
  int g = (orig & 7) * 768 + (orig >> 3);   // bijective: 6144 % 8 == 0
  int bh = g >> 6, qt = g & 63;
  int b = bh / 12, h = bh - b * 12;
  int q0 = qt * 16;
  const short* Qp = Qb + ((size_t)bh * 1024 + q0) * 64;
  const short* Kp = Kb + (size_t)bh * 65536;
  const short* Vp = Vtb + (size_t)bh * 65536;
  const int* mb = amask + b * 1024;

  int t = threadIdx.x, w = t >> 6, lane = t & 63;
  int lr = lane & 15, lg = lane >> 4, lk = lg * 8;

  short8 aq0 = *(const short8*)&Qp[lr * 64 + lk];
  short8 aq1 = *(const short8*)&Qp[lr * 64 + 32 + lk];

  // ---- single QK^T pass: wave w owns cols [w*256, w*256+256), scores in regs ----
  float4v acc[16] = {};
#pragma unroll
  for (int nt = 0; nt < 16; nt++) {
    const short* kp = Kp + (size_t)(w * 256 + nt * 16 + lr) * 64;
    short8 b0 = *(const short8*)&kp[lk];
    short8 b1 = *(const short8*)&kp[32 + lk];
    acc[nt] = mfma16((const short*)&aq0, (const short*)&b0, acc[nt]);
    acc[nt] = mfma16((const short*)&aq1, (const short*)&b1, acc[nt]);
  }

  unsigned mbits = 0;
#pragma unroll
  for (int nt = 0; nt < 16; nt++)
    mbits |= (mb[w * 256 + nt * 16 + lr] != 0 ? 1u : 0u) << nt;

  // ---- row max (rows r = lg*4 + j) ----
  float mx[4] = {-1e30f, -1e30f, -1e30f, -1e30f};
#pragma unroll
  for (int nt = 0; nt < 16; nt++)
#pragma unroll
    for (int j = 0; j < 4; j++) {
      float s = acc[nt][j] * 0.125f;
      if (!((mbits >> nt) & 1)) s = -1e30f;
      acc[nt][j] = s;
      mx[j] = fmaxf(mx[j], s);
    }
#pragma unroll
  for (int j = 0; j < 4; j++) {
#pragma unroll
    for (int off = 1; off < 16; off <<= 1) mx[j] = fmaxf(mx[j], __shfl_xor(mx[j], off));
  }
  if (lr == 0) {
#pragma unroll
    for (int j = 0; j < 4; j++) redmax[w][lg * 4 + j] = mx[j];
  }
  __syncthreads();
  float gmx[4];
#pragma unroll
  for (int j = 0; j < 4; j++) {
    int r = lg * 4 + j;
    gmx[j] = fmaxf(fmaxf(redmax[0][r], redmax[1][r]), fmaxf(redmax[2][r], redmax[3][r]));
  }

  // ---- exp + row sum ----
  float sm[4] = {0.f, 0.f, 0.f, 0.f};
#pragma unroll
  for (int nt = 0; nt < 16; nt++)
#pragma unroll
    for (int j = 0; j < 4; j++) {
      float p = ((mbits >> nt) & 1) ? __expf(acc[nt][j] - gmx[j]) : 0.f;
      acc[nt][j] = p;
      sm[j] += p;
    }
#pragma unroll
  for (int j = 0; j < 4; j++) {
#pragma unroll
    for (int off = 1; off < 16; off <<= 1) sm[j] += __shfl_xor(sm[j], off);
  }
  if (lr == 0) {
#pragma unroll
    for (int j = 0; j < 4; j++) redsum[w][lg * 4 + j] = sm[j];
  }
  __syncthreads();
  float inv[4];
#pragma unroll
  for (int j = 0; j < 4; j++) {
    int r = lg * 4 + j;
    float s = redsum[0][r] + redsum[1][r] + redsum[2][r] + redsum[3][r];
    inv[j] = (s > 0.f) ? 1.f / s : 0.f;
  }

  // ---- normalize -> P (bf16 LDS) ----
#pragma unroll
  for (int nt = 0; nt < 16; nt++) {
    int col = w * 256 + nt * 16 + lr;
#pragma unroll
    for (int j = 0; j < 4; j++)
      P[lg * 4 + j][col] = f2bf(acc[nt][j] * inv[j]);
  }
  __syncthreads();

  // ---- probs write: coalesced nontemporal float4 from P ----
  size_t pbase = ((size_t)bh * 1024 + q0) * 1024;
  {
    int prow = t >> 4;
    int cb = (t & 15) * 4;
    float* orow = probs + pbase + (size_t)prow * 1024;
#pragma unroll
    for (int u = 0; u < 16; u++) {
      int col = cb + u * 64;
      short4v pv = *(const short4v*)&P[prow][col];
      float4v f;
      f.x = bf2f(pv.x); f.y = bf2f(pv.y); f.z = bf2f(pv.z); f.w = bf2f(pv.w);
      __builtin_nontemporal_store(f, (float4v*)&orow[col]);
    }
  }

  // ---- PV dh-split: wave w computes dh in [w*16, w*16+16) over all 1024 k ----
  float4v c0 = {}, c1 = {};
  const short* vrow = Vp + (size_t)(w * 16 + lr) * 1024;
#pragma unroll
  for (int kk = 0; kk < 32; kk += 2) {
    short8 ap0 = *(const short8*)&P[lr][kk * 32 + lk];
    short8 bv0 = *(const short8*)&vrow[kk * 32 + lk];
    c0 = mfma16((const short*)&ap0, (const short*)&bv0, c0);
    short8 ap1 = *(const short8*)&P[lr][(kk + 1) * 32 + lk];
    short8 bv1 = *(const short8*)&vrow[(kk + 1) * 32 + lk];
    c1 = mfma16((const short*)&ap1, (const short*)&bv1, c1);
  }
  c0 = c0 + c1;
#pragma unroll
  for (int j = 0; j < 4; j++)
    ctxf[lg * 4 + j][w * 16 + lr] = c0[j];
  __syncthreads();

  // ---- ctx store: 16 rows x 64 dh, short8 vector stores ----
  if (t < 128) {
    int row = t >> 3, gg = t & 7;
    const float* src = &ctxf[row][gg * 8];
    short8 o;
    o[0] = f2bf(src[0]); o[1] = f2bf(src[1]); o[2] = f2bf(src[2]); o[3] = f2bf(src[3]);
    o[4] = f2bf(src[4]); o[5] = f2bf(src[5]); o[6] = f2bf(src[6]); o[7] = f2bf(src[7]);
    *(short8*)&ctxb[((size_t)(b * 1024 + q0 + row)) * 768 + h * 64 + gg * 8] = o;
  }
}

// ---------------- O projection (NT) + bias + residual -> h fp32 ----------------
__global__ __launch_bounds__(256) void gemm_o(const short* __restrict__ A,
                                              const short* __restrict__ Bw,
                                              const float* __restrict__ bo,
                                              const float* __restrict__ hidden,
                                              float* __restrict__ hout) {
  __shared__ short As[128][32];
  __shared__ short Bs[128][32];
  int m0 = blockIdx.x * 128, n0 = blockIdx.y * 128;
  int t = threadIdx.x, w = t >> 6, lane = t & 63;
  int wm = (w >> 1) * 64, wn = (w & 1) * 64;
  int lr = lane & 15, lk = (lane >> 4) * 8;

  const short* gA = A + (size_t)(m0 + w * 32 + (lane >> 2)) * 768 + (lane & 3) * 8;
  const short* gB = Bw + (size_t)(n0 + w * 32 + (lane >> 2)) * 768 + (lane & 3) * 8;

  float4v acc[4][4] = {};

  for (int k0 = 0; k0 < 768; k0 += 32) {
    gload16(gA, &As[w * 32][0]);
    gload16(gA + 16 * 768, &As[w * 32 + 16][0]);
    gload16(gB, &Bs[w * 32][0]);
    gload16(gB + 16 * 768, &Bs[w * 32 + 16][0]);
    gA += 32; gB += 32;
    __syncthreads();
    short8 a[4], b[4];
#pragma unroll
    for (int i = 0; i < 4; i++) a[i] = *(const short8*)&As[wm + i * 16 + lr][lk];
#pragma unroll
    for (int j = 0; j < 4; j++) b[j] = *(const short8*)&Bs[wn + j * 16 + lr][lk];
#pragma unroll
    for (int i = 0; i < 4; i++)
#pragma unroll
      for (int j = 0; j < 4; j++)
        acc[i][j] = mfma16((const short*)&a[i], (const short*)&b[j], acc[i][j]);
    __syncthreads();
  }

#pragma unroll
  for (int j = 0; j < 4; j++) {
    int gn = n0 + wn + j * 16 + lr;
    float bb = bo[gn];
#pragma unroll
    for (int i = 0; i < 4; i++) {
      int gm0 = m0 + wm + i * 16 + ((lane >> 4) << 2);
#pragma unroll
      for (int jj = 0; jj < 4; jj++) {
        int r = gm0 + jj;
        size_t idx = (size_t)r * 768 + gn;
        hout[idx] = acc[i][j][jj] + bb + hidden[idx];
      }
    }
  }
}

// ---------------- LayerNorm over D=768, float4-vectorized (192 thr/row) ----------------
__global__ __launch_bounds__(192) void lnorm(const float* __restrict__ h,
                                             const float* __restrict__ g,
                                             const float* __restrict__ be,
                                             float* __restrict__ out) {
  int row = blockIdx.x;
  int t = threadIdx.x;
  const float4v* x4 = (const float4v*)(h + (size_t)row * 768);
  float4v v = x4[t];
  float s = v.x + v.y + v.z + v.w;
#pragma unroll
  for (int off = 1; off < 64; off <<= 1) s += __shfl_xor(s, off);
  __shared__ float r1[3], r2[3];
  if ((t & 63) == 0) r1[t >> 6] = s;
  __syncthreads();
  float mean = (r1[0] + r1[1] + r1[2]) * (1.f / 768.f);
  float4v d;
  d.x = v.x - mean; d.y = v.y - mean; d.z = v.z - mean; d.w = v.w - mean;
  float q = d.x * d.x + d.y * d.y + d.z * d.z + d.w * d.w;
#pragma unroll
  for (int off = 1; off < 64; off <<= 1) q += __shfl_xor(q, off);
  if ((t & 63) == 0) r2[t >> 6] = q;
  __syncthreads();
  float var = (r2[0] + r2[1] + r2[2]) * (1.f / 768.f);
  float rr = rsqrtf(var + 1e-12f);
  float4v g4 = ((const float4v*)g)[t];
  float4v b4 = ((const float4v*)be)[t];
  float4v o;
  o.x = d.x * rr * g4.x + b4.x;
  o.y = d.y * rr * g4.y + b4.y;
  o.z = d.z * rr * g4.z + b4.z;
  o.w = d.w * rr * g4.w + b4.w;
  ((float4v*)(out + (size_t)row * 768))[t] = o;
}

extern "C" void kernel_launch(void* const* d_in, const int* in_sizes, int n_in,
                              void* d_out, int out_size, void* d_ws, size_t ws_size,
                              hipStream_t stream) {
  const float* hs    = (const float*)d_in[0];
  const int*   amask = (const int*)d_in[1];
  const float* Wq    = (const float*)d_in[2];
  const float* bq    = (const float*)d_in[3];
  const float* Wk    = (const float*)d_in[4];
  const float* bk    = (const float*)d_in[5];
  const float* Wv    = (const float*)d_in[6];
  const float* bv    = (const float*)d_in[7];
  const float* Wo    = (const float*)d_in[8];
  const float* bo    = (const float*)d_in[9];
  const float* lng   = (const float*)d_in[10];
  const float* lnb   = (const float*)d_in[11];

  char* wsp = (char*)d_ws;
  const size_t NTOK = (size_t)B_ * S_;  // 8192
  short* hsb  = (short*)wsp; wsp += NTOK * D_ * 2;
  short* wqkv = (short*)wsp; wsp += (size_t)3 * D_ * D_ * 2;
  short* wob  = (short*)wsp; wsp += (size_t)D_ * D_ * 2;
  short* Qb   = (short*)wsp; wsp += NTOK * D_ * 2;
  short* Kb   = (short*)wsp; wsp += NTOK * D_ * 2;
  short* Vtb  = (short*)wsp; wsp += NTOK * D_ * 2;
  short* ctxb = (short*)wsp; wsp += NTOK * D_ * 2;
  float* hbuf = (float*)wsp; wsp += NTOK * D_ * 4;

  float* out   = (float*)d_out;
  float* probs = out + NTOK * D_;

  int n4hs = (int)(NTOK * D_ / 4);
  cvt_bf16<<<dim3((n4hs + 255) / 256), dim3(256), 0, stream>>>(hs, hsb, n4hs);
  cvt_w4<<<dim3(4 * 576), dim3(256), 0, stream>>>(Wq, Wk, Wv, Wo, wqkv, wob);

  gemm_qkv<<<dim3(64, 18), dim3(256), 0, stream>>>(hsb, wqkv, bq, bk, bv, Qb, Kb, Vtb);
  attn_fused<<<dim3(6144), dim3(256), 0, stream>>>(Qb, Kb, Vtb, amask, probs, ctxb);
  gemm_o<<<dim3(64, 6), dim3(256), 0, stream>>>(ctxb, wob, bo, hs, hbuf);
  lnorm<<<dim3(8192), dim3(192), 0, stream>>>(hbuf, lng, lnb, out);
}